// Round 3
// baseline (498.205 us; speedup 1.0000x reference)
//
#include <hip/hip_runtime.h>
#include <float.h>

#define NTOK 32768  // 16 * 2048 tokens per modality

// ================= numpy pairwise-sum replica (fp32, PW_BLOCKSIZE=128) ======
// numpy: 8 strided accumulators seeded from first 8 elems, fixed combine tree
// ((r0+r1)+(r2+r3))+((r4+r5)+(r6+r7)); n>128 splits 128/rest. n here is a
// multiple of 8 (64/128/256). __fmul_rn/__fadd_rn block fma-contraction.

__device__ __forceinline__ float pw_sq_block_g(const float* __restrict__ a, int n) {
    float r[8];
    #pragma unroll
    for (int j = 0; j < 8; ++j) r[j] = __fmul_rn(a[j], a[j]);
    for (int i = 8; i < n; i += 8)
        #pragma unroll
        for (int j = 0; j < 8; ++j)
            r[j] = __fadd_rn(r[j], __fmul_rn(a[i + j], a[i + j]));
    return __fadd_rn(__fadd_rn(__fadd_rn(r[0], r[1]), __fadd_rn(r[2], r[3])),
                     __fadd_rn(__fadd_rn(r[4], r[5]), __fadd_rn(r[6], r[7])));
}

// strided (LDS column) version: element i lives at a[i*STRIDE]
template <int STRIDE>
__device__ __forceinline__ float pw_sq_block_s(const float* a, int n) {
    float r[8];
    #pragma unroll
    for (int j = 0; j < 8; ++j) {
        float v = a[j * STRIDE];
        r[j] = __fmul_rn(v, v);
    }
    for (int i = 8; i < n; i += 8)
        #pragma unroll
        for (int j = 0; j < 8; ++j) {
            float v = a[(i + j) * STRIDE];
            r[j] = __fadd_rn(r[j], __fmul_rn(v, v));
        }
    return __fadd_rn(__fadd_rn(__fadd_rn(r[0], r[1]), __fadd_rn(r[2], r[3])),
                     __fadd_rn(__fadd_rn(r[4], r[5]), __fadd_rn(r[6], r[7])));
}

// ---- per-codeword squared norms, numpy-pairwise fp32 ----
__global__ void w2_kernel(const float* __restrict__ W, float* __restrict__ w2,
                          int K, int D) {
    int k = blockIdx.x * blockDim.x + threadIdx.x;
    if (k >= K) return;
    const float* row = W + (size_t)k * D;
    float s = (D > 128)
        ? __fadd_rn(pw_sq_block_g(row, 128), pw_sq_block_g(row + 128, D - 128))
        : pw_sq_block_g(row, D);
    w2[k] = s;
}

// ---- fused distance-GEMM + argmin + gather + loss, one modality ----
template <int D, int K, int TOK>
__global__ __launch_bounds__(256)
void vq_kernel(const float* __restrict__ X, const float* __restrict__ W,
               const float* __restrict__ w2,
               float* __restrict__ q_out, float* __restrict__ idx_out,
               float* __restrict__ loss_out, float inv_nd)
{
    constexpr int KC  = 128;        // codes per K-chunk
    constexpr int DC  = 32;         // dims per D-chunk
    constexpr int TPT = TOK / 16;   // tokens per thread (2 or 4)
    constexpr int XST = TOK + 4;    // padded stride
    constexpr int WST = KC + 4;

    __shared__ float Xs[D][XST];    // X tile, transposed [d][t]
    __shared__ float Ws[DC][WST];   // W chunk, transposed [d][k]
    __shared__ float redv[16][TOK]; // per-ty argmin candidate scores (fp32)
    __shared__ int   redi[16][TOK]; // per-ty argmin candidate indices
    __shared__ float x2s[TOK];      // numpy-pairwise ||x||^2 per token
    __shared__ int   idx_s[TOK];
    __shared__ float lred[4];

    const int tid = threadIdx.x;
    const int tx  = tid & 15;       // token group
    const int ty  = tid >> 4;       // code group (8 codes each)
    const int t0  = blockIdx.x * TOK;

    // stage X tile (transposed)
    for (int i = tid; i < TOK * (D / 4); i += 256) {
        int t  = i / (D / 4);
        int d4 = i % (D / 4);
        const float4 v = *reinterpret_cast<const float4*>(
            X + (size_t)(t0 + t) * D + d4 * 4);
        Xs[d4 * 4 + 0][t] = v.x;
        Xs[d4 * 4 + 1][t] = v.y;
        Xs[d4 * 4 + 2][t] = v.z;
        Xs[d4 * 4 + 3][t] = v.w;
    }
    __syncthreads();

    // numpy-pairwise ||x||^2 per token (exact np.sum(x*x, axis=1) replica)
    if (tid < TOK) {
        const float* col = &Xs[0][tid];
        float s;
        if (D > 128)
            s = __fadd_rn(pw_sq_block_s<XST>(col, 128),
                          pw_sq_block_s<XST>(col + 128 * XST, D - 128));
        else
            s = pw_sq_block_s<XST>(col, D);
        x2s[tid] = s;
    }
    // x2s reads happen after >=2 barriers inside the dc-loop below

    float bestVal = FLT_MAX;
    int   bestIdx = 0;

    for (int kc = 0; kc < K / KC; ++kc) {
        double acc[TPT][8];
        #pragma unroll
        for (int ii = 0; ii < TPT; ++ii)
            #pragma unroll
            for (int j = 0; j < 8; ++j) acc[ii][j] = 0.0;

        for (int dc = 0; dc < D / DC; ++dc) {
            __syncthreads();  // previous chunk / reduction reads done
            // stage W chunk transposed: Ws[d][k]
            for (int i = tid; i < KC * (DC / 4); i += 256) {
                int k  = i / (DC / 4);
                int d4 = i % (DC / 4);
                const float4 v = *reinterpret_cast<const float4*>(
                    W + (size_t)(kc * KC + k) * D + dc * DC + d4 * 4);
                Ws[d4 * 4 + 0][k] = v.x;
                Ws[d4 * 4 + 1][k] = v.y;
                Ws[d4 * 4 + 2][k] = v.z;
                Ws[d4 * 4 + 3][k] = v.w;
            }
            __syncthreads();
            #pragma unroll
            for (int d = 0; d < DC; ++d) {
                double xv[TPT];
                #pragma unroll
                for (int ii = 0; ii < TPT; ++ii)
                    xv[ii] = (double)Xs[dc * DC + d][tx * TPT + ii];
                double wv[8];
                #pragma unroll
                for (int j = 0; j < 8; ++j) wv[j] = (double)Ws[d][ty * 8 + j];
                #pragma unroll
                for (int ii = 0; ii < TPT; ++ii)
                    #pragma unroll
                    for (int j = 0; j < 8; ++j)
                        acc[ii][j] = fma(xv[ii], wv[j], acc[ii][j]);
            }
        }

        // replicate np fp32: d = fl32( fl32(x2 + w2) - 2*fl32(dot) )
        float wqf[8];
        #pragma unroll
        for (int j = 0; j < 8; ++j) wqf[j] = w2[kc * KC + ty * 8 + j];
        #pragma unroll
        for (int ii = 0; ii < TPT; ++ii) {
            const float x2v = x2s[tx * TPT + ii];
            float bv = FLT_MAX; int bj = 0;
            #pragma unroll
            for (int j = 0; j < 8; ++j) {
                float m  = (float)acc[ii][j];            // fl32(true dot)
                float t1 = __fadd_rn(x2v, wqf[j]);       // fp32 x2+w2
                float s  = __fsub_rn(t1, __fmul_rn(2.0f, m));
                if (s < bv) { bv = s; bj = j; }          // strict <, j asc
            }
            redv[ty][tx * TPT + ii] = bv;
            redi[ty][tx * TPT + ii] = kc * KC + ty * 8 + bj;
        }
        __syncthreads();
        if (tid < TOK) {
            // ty ascending == k ascending -> first-occurrence tie-break
            for (int r = 0; r < 16; ++r) {
                float c = redv[r][tid];
                if (c < bestVal) { bestVal = c; bestIdx = redi[r][tid]; }
            }
        }
        // redv/redi/Ws reuse protected by barriers at top of next dc-loop
    }

    if (tid < TOK) {
        idx_out[t0 + tid] = (float)bestIdx;
        idx_s[tid] = bestIdx;
    }
    __syncthreads();

    // gather q = W[idx], write out, accumulate commitment loss partial
    float lp = 0.f;
    for (int i = tid; i < TOK * (D / 4); i += 256) {
        int t  = i / (D / 4);
        int d4 = i % (D / 4);
        int k  = idx_s[t];
        const float4 w = *reinterpret_cast<const float4*>(
            W + (size_t)k * D + d4 * 4);
        float4 x;
        x.x = Xs[d4 * 4 + 0][t];
        x.y = Xs[d4 * 4 + 1][t];
        x.z = Xs[d4 * 4 + 2][t];
        x.w = Xs[d4 * 4 + 3][t];
        *reinterpret_cast<float4*>(q_out + (size_t)(t0 + t) * D + d4 * 4) = w;
        float dx;
        dx = w.x - x.x; lp = fmaf(dx, dx, lp);
        dx = w.y - x.y; lp = fmaf(dx, dx, lp);
        dx = w.z - x.z; lp = fmaf(dx, dx, lp);
        dx = w.w - x.w; lp = fmaf(dx, dx, lp);
    }
    #pragma unroll
    for (int off = 32; off > 0; off >>= 1) lp += __shfl_down(lp, off, 64);
    if ((tid & 63) == 0) lred[tid >> 6] = lp;
    __syncthreads();
    if (tid == 0) {
        float tot = (lred[0] + lred[1]) + (lred[2] + lred[3]);
        atomicAdd(loss_out, tot * inv_nd);
    }
}

extern "C" void kernel_launch(void* const* d_in, const int* in_sizes, int n_in,
                              void* d_out, int out_size, void* d_ws, size_t ws_size,
                              hipStream_t stream)
{
    const float* x_hand = (const float*)d_in[0];
    const float* W_hand = (const float*)d_in[1];
    const float* x_loc  = (const float*)d_in[2];
    const float* W_loc  = (const float*)d_in[3];
    const float* x_ori  = (const float*)d_in[4];
    const float* W_ori  = (const float*)d_in[5];
    const float* x_mov  = (const float*)d_in[6];
    const float* W_mov  = (const float*)d_in[7];
    const float* x_nmf  = (const float*)d_in[8];
    const float* W_nmf  = (const float*)d_in[9];

    float* out = (float*)d_out;
    float* q_hand = out;                 // 32768*256
    float* q_loc  = out + 8388608;       // 32768*128
    float* q_ori  = out + 12582912;      // 32768*64
    float* q_mov  = out + 14680064;      // 32768*128
    float* q_nmf  = out + 18874368;      // 32768*64
    float* i_hand = out + 20971520;
    float* i_loc  = out + 21004288;
    float* i_ori  = out + 21037056;
    float* i_mov  = out + 21069824;
    float* i_nmf  = out + 21102592;
    float* loss   = out + 21135360;

    float* w2      = (float*)d_ws;
    float* w2_hand = w2;
    float* w2_loc  = w2 + 512;
    float* w2_ori  = w2 + 768;
    float* w2_mov  = w2 + 896;
    float* w2_nmf  = w2 + 1152;

    hipMemsetAsync(loss, 0, sizeof(float), stream);

    w2_kernel<<<2, 256, 0, stream>>>(W_hand, w2_hand, 512, 256);
    w2_kernel<<<1, 256, 0, stream>>>(W_loc,  w2_loc,  256, 128);
    w2_kernel<<<1, 256, 0, stream>>>(W_ori,  w2_ori,  128, 64);
    w2_kernel<<<1, 256, 0, stream>>>(W_mov,  w2_mov,  256, 128);
    w2_kernel<<<1, 256, 0, stream>>>(W_nmf,  w2_nmf,  128, 64);

    vq_kernel<256, 512, 32><<<NTOK / 32, 256, 0, stream>>>(
        x_hand, W_hand, w2_hand, q_hand, i_hand, loss,
        1.0f / (32768.0f * 256.0f));
    vq_kernel<128, 256, 64><<<NTOK / 64, 256, 0, stream>>>(
        x_loc, W_loc, w2_loc, q_loc, i_loc, loss,
        1.0f / (32768.0f * 128.0f));
    vq_kernel<64, 128, 64><<<NTOK / 64, 256, 0, stream>>>(
        x_ori, W_ori, w2_ori, q_ori, i_ori, loss,
        1.0f / (32768.0f * 64.0f));
    vq_kernel<128, 256, 64><<<NTOK / 64, 256, 0, stream>>>(
        x_mov, W_mov, w2_mov, q_mov, i_mov, loss,
        1.0f / (32768.0f * 128.0f));
    vq_kernel<64, 128, 64><<<NTOK / 64, 256, 0, stream>>>(
        x_nmf, W_nmf, w2_nmf, q_nmf, i_nmf, loss,
        1.0f / (32768.0f * 64.0f));
}